// Round 1
// baseline (165.344 us; speedup 1.0000x reference)
//
#include <hip/hip_runtime.h>

// Per-clause softmax-attention pooling.
// B=64, T=512, D=768, C=31 -> 32 segments per batch; segments partition [0,T).
// Segment lengths are small (<= ~30 tokens), so one block per (batch, segment).

#define B_ 64
#define T_ 512
#define D_ 768
#define C_ 31
#define NSEG 32  // C+1

// block = 192 threads (3 waves). 192 * 4 = 768 = D, one float4 per thread.
__global__ __launch_bounds__(192) void seg_softmax_pool(
    const float* __restrict__ hidden,    // [B, T, D]
    const int*   __restrict__ clause_b,  // [B, C]
    const float* __restrict__ w5,        // [D] (D x 1)
    const float* __restrict__ b5,        // [1]
    float*       __restrict__ out)       // [B, NSEG, D]
{
    const int blk  = blockIdx.x;
    const int b    = blk >> 5;      // / NSEG
    const int j    = blk & 31;      // % NSEG
    const int tid  = threadIdx.x;
    const int wave = tid >> 6;
    const int lane = tid & 63;

    const int start = (j == 0)  ? 0  : clause_b[b * C_ + j - 1];
    const int end   = (j == C_) ? T_ : clause_b[b * C_ + j];
    const int L     = end - start;   // 1..~30 by construction (<= T_ worst case)

    __shared__ float s_scores[T_];   // 2 KB, generous upper bound

    const float* hseg = hidden + ((size_t)b * T_ + start) * D_;

    // ---------------- Phase 1: scores[t] = <h[t,:], w5> + b5 ----------------
    // Wave (t % 3) owns token t. Lane covers d = {4*lane, 4*lane+256, 4*lane+512}.
    const float4 wv0 = *(const float4*)(w5 + 4 * lane);
    const float4 wv1 = *(const float4*)(w5 + 4 * lane + 256);
    const float4 wv2 = *(const float4*)(w5 + 4 * lane + 512);
    const float  bias = b5[0];

    for (int t = wave; t < L; t += 3) {
        const float* hp = hseg + (size_t)t * D_;
        const float4 h0 = *(const float4*)(hp + 4 * lane);
        const float4 h1 = *(const float4*)(hp + 4 * lane + 256);
        const float4 h2 = *(const float4*)(hp + 4 * lane + 512);
        float p = h0.x * wv0.x + h0.y * wv0.y + h0.z * wv0.z + h0.w * wv0.w
                + h1.x * wv1.x + h1.y * wv1.y + h1.z * wv1.z + h1.w * wv1.w
                + h2.x * wv2.x + h2.y * wv2.y + h2.z * wv2.z + h2.w * wv2.w;
        // wave-64 butterfly reduce
        #pragma unroll
        for (int off = 32; off > 0; off >>= 1)
            p += __shfl_xor(p, off, 64);
        if (lane == 0) s_scores[t] = p + bias;
    }
    __syncthreads();

    // ---------------- Phase 2: softmax weights + weighted pooling ----------------
    // Every thread redundantly scans the (tiny) score list: LDS broadcast reads are free.
    float m = -INFINITY;
    for (int t = 0; t < L; ++t) m = fmaxf(m, s_scores[t]);
    float denom = 0.0f;
    for (int t = 0; t < L; ++t) denom += __expf(s_scores[t] - m);
    const float inv = 1.0f / denom;

    // Thread tid owns output elements d = 4*tid .. 4*tid+3.
    float4 acc = make_float4(0.f, 0.f, 0.f, 0.f);
    const float* hp = hseg + 4 * tid;
    for (int t = 0; t < L; ++t) {
        const float  w = __expf(s_scores[t] - m);
        const float4 h = *(const float4*)(hp + (size_t)t * D_);
        acc.x += w * h.x;
        acc.y += w * h.y;
        acc.z += w * h.z;
        acc.w += w * h.w;
    }
    acc.x *= inv; acc.y *= inv; acc.z *= inv; acc.w *= inv;

    float4* op = (float4*)(out + ((size_t)b * NSEG + j) * D_ + 4 * tid);
    *op = acc;
}

extern "C" void kernel_launch(void* const* d_in, const int* in_sizes, int n_in,
                              void* d_out, int out_size, void* d_ws, size_t ws_size,
                              hipStream_t stream) {
    const float* hidden   = (const float*)d_in[0];
    const int*   clause_b = (const int*)d_in[1];
    const float* w5       = (const float*)d_in[2];
    const float* b5       = (const float*)d_in[3];
    float*       out      = (float*)d_out;

    const int nblocks = B_ * NSEG;  // 2048
    seg_softmax_pool<<<nblocks, 192, 0, stream>>>(hidden, clause_b, w5, b5, out);
}